// Round 6
// baseline (16.284 us; speedup 1.0000x reference)
//
#include <hip/hip_runtime.h>
#include <math.h>

#define DD 15          // feature dim
#define DP 20          // padded LDS row stride (80B, float4-aligned)
#define LL 64          // leaves
#define NCC 10         // num classes
#define NTREE 63       // internal nodes only (levels 0..5)
#define EPB 4          // batch elements per block (1 per wave)

// ---- DPP cross-lane (VALU pipe, no LDS) ----
__device__ __forceinline__ float dpp_xor1(float x) {   // quad_perm [1,0,3,2]
    return __int_as_float(__builtin_amdgcn_update_dpp(0, __float_as_int(x), 0xB1, 0xF, 0xF, true));
}
__device__ __forceinline__ float dpp_xor2(float x) {   // quad_perm [2,3,0,1]
    return __int_as_float(__builtin_amdgcn_update_dpp(0, __float_as_int(x), 0x4E, 0xF, 0xF, true));
}
__device__ __forceinline__ float dpp_hmirror(float x) { // row_half_mirror: u -> u^7 within 8
    return __int_as_float(__builtin_amdgcn_update_dpp(0, __float_as_int(x), 0x141, 0xF, 0xF, true));
}

// combine at one parent: 8 lanes cooperate.
// k = t&1 (W matrix), qr = (t>>1)&3 (4 A-rows), u = t&7 (2 output dims)
__device__ __forceinline__ void combine8_core(const float* Lrow, const float* Rrow,
                                              const float w[4][DD], int k, int qr, int u,
                                              float& o0, float& o1)
{
    float4 R0 = ((const float4*)Rrow)[0];
    float4 R1 = ((const float4*)Rrow)[1];
    float4 R2 = ((const float4*)Rrow)[2];
    float4 R3 = ((const float4*)Rrow)[3];          // .w = pad col15 = 0
    float4 Aq = ((const float4*)Lrow)[qr];         // A dims 4qr..4qr+3 (row15 pad = 0)
    float Bv[DD] = {R0.x,R0.y,R0.z,R0.w, R1.x,R1.y,R1.z,R1.w,
                    R2.x,R2.y,R2.z,R2.w, R3.x,R3.y,R3.z};
    float Av[4] = {Aq.x, Aq.y, Aq.z, Aq.w};

    float p = 0.f;
    #pragma unroll
    for (int ri = 0; ri < 4; ++ri) {
        float dA = 0.f, dB = 0.f;                  // 2-way split: chain depth 8 not 15
        #pragma unroll
        for (int j = 0; j < 8; ++j)  dA = fmaf(w[ri][j], Bv[j], dA);
        #pragma unroll
        for (int j = 8; j < DD; ++j) dB = fmaf(w[ri][j], Bv[j], dB);
        p = fmaf(Av[ri], dA + dB, p);              // invalid row 15: w==0, Av==0
    }
    // reduce partials over qr bits (1,2) and swap k — all DPP
    float a    = p + dpp_xor2(p);
    float hma  = dpp_hmirror(a);
    float self = a + dpp_xor1(hma);
    float oth  = dpp_xor1(a) + hma;
    float mx = fmaxf(self, oth);
    float es = __expf(self - mx), eo = __expf(oth - mx);
    float rs = __builtin_amdgcn_rcpf(es + eo);
    float aS = es * rs, aO = eo * rs;
    float a0 = (k == 0) ? aS : aO;                 // alpha for W0 (left child)
    float a1 = (k == 0) ? aO : aS;

    float2 lm = ((const float2*)Lrow)[u];          // dims 2u, 2u+1
    float2 rm = ((const float2*)Rrow)[u];
    float v0 = a0 * lm.x + a1 * rm.x;
    float v1 = a0 * lm.y + a1 * rm.y;              // u==7: dim15 = 0
    float ss = v0 * v0 + v1 * v1;
    ss += dpp_xor1(ss);
    ss += dpp_xor2(ss);
    ss += dpp_hmirror(ss);
    float inv = __builtin_amdgcn_rsqf(ss * (1.0f / DD) + 1e-6f);
    o0 = v0 * inv; o1 = v1 * inv;
}

// ---- query level 5: boundary nodes; children are leaves (nemb rows or inf) ----
__device__ __forceinline__ void query_level5(float (*tw)[DP], const float (*nemb)[DP],
                                             const float w[4][DD], int t, int k, int qr, int u,
                                             int ql, int qh, int xq1, int xq2)
{
    const int g2 = (t >> 3) & 1;
    int bnd = g2 ? qh : ql;
    int piB = bnd >> 1;
    int lo = 2 * piB, hi = lo + 1;
    bool full = (ql <= lo) && (qh >= hi);
    bool d1 = (ql > lo) || (qh < lo);
    bool d2 = (ql > hi) || (qh < hi);
    const float* Lrow = d1 ? &nemb[NCC][0] : &nemb[xq1][0];
    const float* Rrow = d2 ? &nemb[NCC][0] : &nemb[xq2][0];
    float o0, o1;
    combine8_core(Lrow, Rrow, w, k, qr, u, o0, o1);
    bool we = (!full) && (t < 16) && (g2 == 0 || piB != (ql >> 1));
    if (we) ((float2*)&tw[31 + piB][0])[u] = make_float2(o0, o1);
}

// ---- generic query (levels 1..4): children in tree ----
template<int LVL>
__device__ __forceinline__ void query_level(float (*tw)[DP], const float (*nemb)[DP],
                                            const float w[4][DD], int t, int k, int qr, int u,
                                            int ql, int qh)
{
    constexpr int first = (1 << LVL) - 1;
    constexpr int sh = 6 - LVL;
    constexpr int shc = sh - 1;
    const int g2 = (t >> 3) & 1;
    int bnd = g2 ? qh : ql;
    int pi = bnd >> sh;
    int lo = pi << sh, hi = lo + (1 << sh) - 1;
    bool full = (ql <= lo) && (qh >= hi);
    int p = first + pi;
    int ci1 = 2 * pi, ci2 = 2 * pi + 1;
    int lo1 = ci1 << shc, hi1 = lo1 + (1 << shc) - 1;
    int lo2 = ci2 << shc, hi2 = lo2 + (1 << shc) - 1;
    bool d1 = (ql > hi1) || (qh < lo1);
    bool d2 = (ql > hi2) || (qh < lo2);
    const float* Lrow = d1 ? &nemb[NCC][0] : &tw[2 * p + 1][0];
    const float* Rrow = d2 ? &nemb[NCC][0] : &tw[2 * p + 2][0];
    float o0, o1;
    combine8_core(Lrow, Rrow, w, k, qr, u, o0, o1);
    bool we = (!full) && (t < 16) && (g2 == 0 || pi != (ql >> sh));
    if (we) ((float2*)&tw[p][0])[u] = make_float2(o0, o1);
}

// ---- query level 0: always write (covers the root-full case) ----
__device__ __forceinline__ void query_level0(float (*tw)[DP], const float (*nemb)[DP],
                                             const float w[4][DD], int t, int k, int qr, int u,
                                             int ql, int qh)
{
    bool d1 = (ql > 31);             // left child [0,31]
    bool d2 = (qh < 32);             // right child [32,63]
    const float* Lrow = d1 ? &nemb[NCC][0] : &tw[1][0];
    const float* Rrow = d2 ? &nemb[NCC][0] : &tw[2][0];
    float o0, o1;
    combine8_core(Lrow, Rrow, w, k, qr, u, o0, o1);
    if (t < 8) ((float2*)&tw[0][0])[u] = make_float2(o0, o1);
}

extern "C" __global__ __attribute__((amdgpu_flat_work_group_size(256, 256)))
void seg_tree_kernel(
    const float* __restrict__ emb,
    const float* __restrict__ W_lin,
    const float* __restrict__ W_rule,
    const int*  __restrict__ x,
    const int*  __restrict__ qlo_g,
    const int*  __restrict__ qhi_g,
    float* __restrict__ out,
    int bsz)
{
    __shared__ __align__(16) float nemb[NCC + 1][DP];
    __shared__ __align__(16) float tree[EPB][NTREE][DP];

    const int tb = threadIdx.x;
    const int wv = tb >> 6;
    const int t  = tb & 63;
    int b = blockIdx.x * EPB + wv;
    const bool active = (b < bsz);
    if (!active) b = bsz - 1;                 // clamp: redundant work, store guarded

    const int k = t & 1, qr = (t >> 1) & 3, u = t & 7, g = t >> 3;
    float (*tw)[DP] = tree[wv];

    // wave-uniform query bounds in SGPRs -> scalar masks/branches
    const int ql = __builtin_amdgcn_readfirstlane(qlo_g[b]);
    const int qh = __builtin_amdgcn_readfirstlane(qhi_g[b]);

    // containment ranges per level: build node iff range subset of [ql,qh]
    const int plo5 = (ql + 1) >> 1, phi5 = (qh + 1) >> 1;
    const int plo4 = (ql + 3) >> 2, phi4 = (qh + 1) >> 2;
    const int plo3 = (ql + 7) >> 3, phi3 = (qh + 1) >> 3;
    const int plo2 = (ql + 15) >> 4, phi2 = (qh + 1) >> 4;
    const int plo1 = (ql + 31) >> 5, phi1 = (qh + 1) >> 5;

    int xA[4], xB[4];
    #pragma unroll
    for (int st = 0; st < 4; ++st) {
        xA[st] = x[b * LL + st * 16 + 2 * g];
        xB[st] = x[b * LL + st * 16 + 2 * g + 1];
    }
    int piB = (((t >> 3) & 1) ? qh : ql) >> 1;
    int xq1 = x[b * LL + 2 * piB], xq2 = x[b * LL + 2 * piB + 1];

    // ---- per-lane weights: rows 4qr..4qr+3 of W_rule[k]; row 15 zeroed ----
    float w[4][DD];
    #pragma unroll
    for (int ri = 0; ri < 4; ++ri) {
        int i = 4 * qr + ri;
        bool valid = (i < DD);
        const float* src = W_rule + k * DD * DD + (valid ? i * DD : 0);
        #pragma unroll
        for (int j = 0; j < DD; ++j) w[ri][j] = valid ? src[j] : 0.0f;
    }
    #pragma unroll
    for (int ri = 0; ri < 4; ++ri)
        #pragma unroll
        for (int j = 0; j < DD; ++j)
            asm("" : "+v"(w[ri][j]));          // non-volatile pin: materialize once

    // ---- normalize emb rows into LDS once per block; pad col15 = 0 ----
    if (tb < NCC + 1) {
        float v[DD]; float ssum = 0.f;
        #pragma unroll
        for (int d = 0; d < DD; ++d) { v[d] = emb[tb * DD + d]; ssum += v[d] * v[d]; }
        float inv = __builtin_amdgcn_rsqf(ssum * (1.0f / DD) + 1e-6f);
        #pragma unroll
        for (int d = 0; d < DD; ++d) nemb[tb][d] = v[d] * inv;
        nemb[tb][DD] = 0.0f;
    }
    __syncthreads();                           // the only barrier

    // ---- build L5 (only contained parents), then fused query levels ----
    {
        int st_lo = plo5 >> 3, st_hi = (phi5 + 7) >> 3;
        for (int st = st_lo; st < st_hi; ++st) {
            int pi0 = st * 8 + g;
            float o0, o1;
            combine8_core(&nemb[xA[st]][0], &nemb[xB[st]][0], w, k, qr, u, o0, o1);
            if (pi0 >= plo5 && pi0 < phi5)
                ((float2*)&tw[31 + pi0][0])[u] = make_float2(o0, o1);
        }
    }
    query_level5(tw, nemb, w, t, k, qr, u, ql, qh, xq1, xq2);

    {   // build L4: nodes 15+pi, children rows 31+2pi / 32+2pi
        int st_lo = plo4 >> 3, st_hi = (phi4 + 7) >> 3;
        for (int st = st_lo; st < st_hi; ++st) {
            int pi0 = st * 8 + g;                 // <= 15 since phi4 <= 16
            float o0, o1;
            combine8_core(&tw[31 + 2 * pi0][0], &tw[32 + 2 * pi0][0], w, k, qr, u, o0, o1);
            if (pi0 >= plo4 && pi0 < phi4)
                ((float2*)&tw[15 + pi0][0])[u] = make_float2(o0, o1);
        }
    }
    query_level<4>(tw, nemb, w, t, k, qr, u, ql, qh);

    if (phi3 > plo3) {                            // build L3: nodes 7+pi (pi=g<8)
        float o0, o1;
        combine8_core(&tw[15 + 2 * g][0], &tw[16 + 2 * g][0], w, k, qr, u, o0, o1);
        if (g >= plo3 && g < phi3)
            ((float2*)&tw[7 + g][0])[u] = make_float2(o0, o1);
    }
    query_level<3>(tw, nemb, w, t, k, qr, u, ql, qh);

    if (phi2 > plo2) {                            // build L2: nodes 3+pi (pi=g&3)
        int pi = g & 3;
        float o0, o1;
        combine8_core(&tw[7 + 2 * pi][0], &tw[8 + 2 * pi][0], w, k, qr, u, o0, o1);
        if (g < 4 && pi >= plo2 && pi < phi2)
            ((float2*)&tw[3 + pi][0])[u] = make_float2(o0, o1);
    }
    query_level<2>(tw, nemb, w, t, k, qr, u, ql, qh);

    if (phi1 > plo1) {                            // build L1: nodes 1+pi (pi=g&1)
        int pi = g & 1;
        float o0, o1;
        combine8_core(&tw[3 + 2 * pi][0], &tw[4 + 2 * pi][0], w, k, qr, u, o0, o1);
        if (g < 2 && pi >= plo1 && pi < phi1)
            ((float2*)&tw[1 + pi][0])[u] = make_float2(o0, o1);
    }
    query_level<1>(tw, nemb, w, t, k, qr, u, ql, qh);

    query_level0(tw, nemb, w, t, k, qr, u, ql, qh);

    // ---- output: out[b] = Q(root) @ W_lin.T ----
    if (active && t < NCC) {
        float acc = 0.f;
        #pragma unroll
        for (int d = 0; d < DD; ++d) acc = fmaf(tw[0][d], W_lin[t * DD + d], acc);
        out[b * NCC + t] = acc;
    }
}

extern "C" void kernel_launch(void* const* d_in, const int* in_sizes, int n_in,
                              void* d_out, int out_size, void* d_ws, size_t ws_size,
                              hipStream_t stream) {
    const float* emb    = (const float*)d_in[0];
    const float* W_lin  = (const float*)d_in[1];
    const float* W_rule = (const float*)d_in[2];
    const int*   x      = (const int*)d_in[3];
    const int*   qlo    = (const int*)d_in[4];
    const int*   qhi    = (const int*)d_in[5];
    float* outp = (float*)d_out;

    int bsz = in_sizes[3] / LL;               // 2048
    int nblk = (bsz + EPB - 1) / EPB;         // 512
    seg_tree_kernel<<<dim3(nblk), dim3(256), 0, stream>>>(
        emb, W_lin, W_rule, x, qlo, qhi, outp, bsz);
}

// Round 7
// 15.502 us; speedup vs baseline: 1.0505x; 1.0505x over previous
//
#include <hip/hip_runtime.h>
#include <math.h>

#define DD 15          // feature dim
#define DP 20          // padded LDS row stride (80B, float4-aligned)
#define LL 64          // leaves
#define NCC 10         // num classes
#define NTREE 63       // internal nodes only (levels 0..5)
#define EPB 4          // batch elements per block (1 per wave)

// ---- DPP cross-lane (VALU pipe, no LDS) ----
__device__ __forceinline__ float dpp_xor1(float x) {   // quad_perm [1,0,3,2]
    return __int_as_float(__builtin_amdgcn_update_dpp(0, __float_as_int(x), 0xB1, 0xF, 0xF, true));
}
__device__ __forceinline__ float dpp_xor2(float x) {   // quad_perm [2,3,0,1]
    return __int_as_float(__builtin_amdgcn_update_dpp(0, __float_as_int(x), 0x4E, 0xF, 0xF, true));
}
__device__ __forceinline__ float dpp_hmirror(float x) { // row_half_mirror: u -> u^7 within 8
    return __int_as_float(__builtin_amdgcn_update_dpp(0, __float_as_int(x), 0x141, 0xF, 0xF, true));
}

// child registers for one combine (loaded in the phase's batch-load section)
struct CR {
    float4 Lq;              // L dims 4qr..4qr+3
    float4 R0, R1, R2, R3;  // R full (col 15 = pad = 0)
    float2 lm, rm;          // L,R dims 2u,2u+1
};

__device__ __forceinline__ CR load_children(const float* Lrow, const float* Rrow, int qr, int u) {
    CR c;
    c.Lq = ((const float4*)Lrow)[qr];
    c.R0 = ((const float4*)Rrow)[0];
    c.R1 = ((const float4*)Rrow)[1];
    c.R2 = ((const float4*)Rrow)[2];
    c.R3 = ((const float4*)Rrow)[3];
    c.lm = ((const float2*)Lrow)[u];
    c.rm = ((const float2*)Rrow)[u];
    return c;
}

// compute combine from preloaded regs. k = t&1 (W matrix). Output o0,o1 = dims 2u,2u+1.
__device__ __forceinline__ void compute_combine(const CR& c, const float w[4][DD], int k,
                                                float& o0, float& o1)
{
    float Bv[DD] = {c.R0.x,c.R0.y,c.R0.z,c.R0.w, c.R1.x,c.R1.y,c.R1.z,c.R1.w,
                    c.R2.x,c.R2.y,c.R2.z,c.R2.w, c.R3.x,c.R3.y,c.R3.z};
    float Av[4] = {c.Lq.x, c.Lq.y, c.Lq.z, c.Lq.w};

    float p = 0.f;
    #pragma unroll
    for (int ri = 0; ri < 4; ++ri) {
        float dA = 0.f, dB = 0.f;                  // split chain: depth 8 not 15
        #pragma unroll
        for (int j = 0; j < 8; ++j)  dA = fmaf(w[ri][j], Bv[j], dA);
        #pragma unroll
        for (int j = 8; j < DD; ++j) dB = fmaf(w[ri][j], Bv[j], dB);
        p = fmaf(Av[ri], dA + dB, p);              // invalid row 15: w==0, Av==0
    }
    // reduce partials over qr bits (1,2), fetch partner-k logit — all DPP
    float a    = p + dpp_xor2(p);
    float hma  = dpp_hmirror(a);
    float self = a + dpp_xor1(hma);
    float oth  = dpp_xor1(a) + hma;
    // softmax of 2 == sigmoid(self - oth): one exp instead of max+2*exp
    float aS = __builtin_amdgcn_rcpf(1.0f + __expf(oth - self));
    float aO = 1.0f - aS;
    float a0 = (k == 0) ? aS : aO;                 // alpha for W0 (left child)
    float a1 = (k == 0) ? aO : aS;

    float v0 = fmaf(a0, c.lm.x, a1 * c.rm.x);
    float v1 = fmaf(a0, c.lm.y, a1 * c.rm.y);      // u==7: dim15 = 0
    float ss = v0 * v0 + v1 * v1;
    ss += dpp_xor1(ss);
    ss += dpp_xor2(ss);
    ss += dpp_hmirror(ss);
    float inv = __builtin_amdgcn_rsqf(ss * (1.0f / DD) + 1e-6f);
    o0 = v0 * inv; o1 = v1 * inv;
}

// ---- generic phase for levels 4..1: batch-load (build + query), compute, write ----
template<int LVL>
__device__ __forceinline__ void phase(float (*tw)[DP], const float (*nemb)[DP],
                                      const float w[4][DD], int t, int k, int qr, int u, int g,
                                      int ql, int qh)
{
    constexpr int n = 1 << LVL, first = n - 1;
    constexpr int NB = (n > 8) ? (n / 8) : 1;
    constexpr int sh = 6 - LVL, shc = sh - 1;

    // ---- batch loads: build children (level LVL+1 rows) ----
    CR cb[NB]; int pb[NB];
    #pragma unroll
    for (int st = 0; st < NB; ++st) {
        int pi = (n >= 8) ? (st * 8 + g) : (g & (n - 1));
        int p = first + pi;
        pb[st] = p;
        cb[st] = load_children(&tw[2 * p + 1][0], &tw[2 * p + 2][0], qr, u);
    }
    // ---- batch loads: query boundary node (children also level LVL+1) ----
    const int g2 = (t >> 3) & 1;
    int bnd = g2 ? qh : ql;
    int piq = bnd >> sh;
    int pq = first + piq;
    int lo = piq << sh, hi = lo + (1 << sh) - 1;
    bool full = (ql <= lo) && (qh >= hi);
    int lo1 = (2 * piq) << shc,     hi1 = lo1 + (1 << shc) - 1;
    int lo2 = (2 * piq + 1) << shc, hi2 = lo2 + (1 << shc) - 1;
    bool d1 = (ql > hi1) || (qh < lo1);
    bool d2 = (ql > hi2) || (qh < lo2);
    const float* Lp = d1 ? &nemb[NCC][0] : &tw[2 * pq + 1][0];
    const float* Rp = d2 ? &nemb[NCC][0] : &tw[2 * pq + 2][0];
    CR cq = load_children(Lp, Rp, qr, u);

    // ---- compute + write (writes trail all loads; next phase reads them) ----
    #pragma unroll
    for (int st = 0; st < NB; ++st) {
        float o0, o1;
        compute_combine(cb[st], w, k, o0, o1);
        if (n >= 8 || g < n)
            ((float2*)&tw[pb[st]][0])[u] = make_float2(o0, o1);
    }
    {
        float o0, o1;
        compute_combine(cq, w, k, o0, o1);
        bool we = (!full) && (t < 16) && (g2 == 0 || piq != (ql >> sh));
        if (we) ((float2*)&tw[pq][0])[u] = make_float2(o0, o1);
    }
}

extern "C" __global__ __attribute__((amdgpu_flat_work_group_size(256, 256)))
void seg_tree_kernel(
    const float* __restrict__ emb,
    const float* __restrict__ W_lin,
    const float* __restrict__ W_rule,
    const int*  __restrict__ x,
    const int*  __restrict__ qlo_g,
    const int*  __restrict__ qhi_g,
    float* __restrict__ out,
    int bsz)
{
    __shared__ __align__(16) float nemb[NCC + 1][DP];
    __shared__ __align__(16) float tree[EPB][NTREE][DP];

    const int tb = threadIdx.x;
    const int wv = tb >> 6;
    const int t  = tb & 63;
    int b = blockIdx.x * EPB + wv;
    const bool active = (b < bsz);
    if (!active) b = bsz - 1;                 // clamp: redundant work, store guarded

    const int k = t & 1, qr = (t >> 1) & 3, u = t & 7, g = t >> 3;
    float (*tw)[DP] = tree[wv];

    const int ql = qlo_g[b], qh = qhi_g[b];

    // prefetch x indices for build L5 and query L5
    int xA[4], xB[4];
    #pragma unroll
    for (int st = 0; st < 4; ++st) {
        xA[st] = x[b * LL + st * 16 + 2 * g];
        xB[st] = x[b * LL + st * 16 + 2 * g + 1];
    }
    const int g2i = (t >> 3) & 1;
    int piB = (g2i ? qh : ql) >> 1;
    int xq1 = x[b * LL + 2 * piB], xq2 = x[b * LL + 2 * piB + 1];

    // ---- per-lane weights: rows 4qr..4qr+3 of W_rule[k]; row 15 zeroed ----
    float w[4][DD];
    #pragma unroll
    for (int ri = 0; ri < 4; ++ri) {
        int i = 4 * qr + ri;
        bool valid = (i < DD);
        const float* src = W_rule + k * DD * DD + (valid ? i * DD : 0);
        #pragma unroll
        for (int j = 0; j < DD; ++j) w[ri][j] = valid ? src[j] : 0.0f;
    }
    #pragma unroll
    for (int ri = 0; ri < 4; ++ri)
        #pragma unroll
        for (int j = 0; j < DD; ++j)
            asm("" : "+v"(w[ri][j]));          // materialize once in VGPRs

    // ---- W_lin row for the epilogue (preloaded so it doesn't trail) ----
    float wl[DD];
    {
        const float* wlp = W_lin + ((t < NCC) ? t : 0) * DD;
        #pragma unroll
        for (int d = 0; d < DD; ++d) wl[d] = wlp[d];
    }

    // ---- normalize emb rows into LDS once per block; pad col15 = 0 ----
    if (tb < NCC + 1) {
        float v[DD]; float ssum = 0.f;
        #pragma unroll
        for (int d = 0; d < DD; ++d) { v[d] = emb[tb * DD + d]; ssum += v[d] * v[d]; }
        float inv = __builtin_amdgcn_rsqf(ssum * (1.0f / DD) + 1e-6f);
        #pragma unroll
        for (int d = 0; d < DD; ++d) nemb[tb][d] = v[d] * inv;
        nemb[tb][DD] = 0.0f;
    }
    __syncthreads();                           // the only barrier

    // ================= P5: build L5 (4 stages) + query L5, batched =================
    {
        CR c5[4];
        #pragma unroll
        for (int st = 0; st < 4; ++st)
            c5[st] = load_children(&nemb[xA[st]][0], &nemb[xB[st]][0], qr, u);
        // query L5 loads (children are leaves)
        int lo = 2 * piB, hi = lo + 1;
        bool full5 = (ql <= lo) && (qh >= hi);
        bool d1 = (ql > lo) || (qh < lo);
        bool d2 = (ql > hi) || (qh < hi);
        const float* Lp = d1 ? &nemb[NCC][0] : &nemb[xq1][0];
        const float* Rp = d2 ? &nemb[NCC][0] : &nemb[xq2][0];
        CR cq5 = load_children(Lp, Rp, qr, u);

        #pragma unroll
        for (int st = 0; st < 4; ++st) {
            float o0, o1;
            compute_combine(c5[st], w, k, o0, o1);
            ((float2*)&tw[31 + st * 8 + g][0])[u] = make_float2(o0, o1);
        }
        {
            float o0, o1;
            compute_combine(cq5, w, k, o0, o1);
            bool we = (!full5) && (t < 16) && (g2i == 0 || piB != (ql >> 1));
            if (we) ((float2*)&tw[31 + piB][0])[u] = make_float2(o0, o1);
        }
    }

    // ================= P4..P1 =================
    phase<4>(tw, nemb, w, t, k, qr, u, g, ql, qh);
    phase<3>(tw, nemb, w, t, k, qr, u, g, ql, qh);
    phase<2>(tw, nemb, w, t, k, qr, u, g, ql, qh);
    phase<1>(tw, nemb, w, t, k, qr, u, g, ql, qh);

    // ================= P0: query root (always write; covers root-full) ==============
    {
        bool d1 = (ql > 31);                   // left child [0,31]
        bool d2 = (qh < 32);                   // right child [32,63]
        const float* Lp = d1 ? &nemb[NCC][0] : &tw[1][0];
        const float* Rp = d2 ? &nemb[NCC][0] : &tw[2][0];
        CR c0 = load_children(Lp, Rp, qr, u);
        float o0, o1;
        compute_combine(c0, w, k, o0, o1);
        if (t < 8) ((float2*)&tw[0][0])[u] = make_float2(o0, o1);
    }

    // ---- output: out[b] = Q(root) @ W_lin.T ----
    if (active && t < NCC) {
        float acc = 0.f;
        #pragma unroll
        for (int d = 0; d < DD; ++d) acc = fmaf(tw[0][d], wl[d], acc);
        out[b * NCC + t] = acc;
    }
}

extern "C" void kernel_launch(void* const* d_in, const int* in_sizes, int n_in,
                              void* d_out, int out_size, void* d_ws, size_t ws_size,
                              hipStream_t stream) {
    const float* emb    = (const float*)d_in[0];
    const float* W_lin  = (const float*)d_in[1];
    const float* W_rule = (const float*)d_in[2];
    const int*   x      = (const int*)d_in[3];
    const int*   qlo    = (const int*)d_in[4];
    const int*   qhi    = (const int*)d_in[5];
    float* outp = (float*)d_out;

    int bsz = in_sizes[3] / LL;               // 2048
    int nblk = (bsz + EPB - 1) / EPB;         // 512
    seg_tree_kernel<<<dim3(nblk), dim3(256), 0, stream>>>(
        emb, W_lin, W_rule, x, qlo, qhi, outp, bsz);
}